// Round 5
// baseline (730.156 us; speedup 1.0000x reference)
//
#include <hip/hip_runtime.h>

#define NI 64      // instances
#define CH 64      // channels
#define EPSV 1e-5f
#define KB 32      // blocks per instance in fused kernel
#define PADT 66    // padded LDS table row for k_out (fallback)
#define PADW 65    // fallback-path padding

typedef float v4f __attribute__((ext_vector_type(4)));

#define LD_AGENT(p)     __hip_atomic_load((p), __ATOMIC_RELAXED, __HIP_MEMORY_SCOPE_AGENT)
#define LD_ACQ(p)       __hip_atomic_load((p), __ATOMIC_ACQUIRE, __HIP_MEMORY_SCOPE_AGENT)
#define ST_AGENT(p, v)  __hip_atomic_store((p), (v), __ATOMIC_RELAXED, __HIP_MEMORY_SCOPE_AGENT)
#define ST_REL(p, v)    __hip_atomic_store((p), (v), __ATOMIC_RELEASE, __HIP_MEMORY_SCOPE_AGENT)

// ---- K0: per-instance counts ----
__global__ __launch_bounds__(256) void k_hist(const int* __restrict__ seg,
                                              unsigned* __restrict__ hist, int n) {
  __shared__ unsigned h[NI];
  const int t = threadIdx.x;
  if (t < NI) h[t] = 0u;
  __syncthreads();
  const int stride = gridDim.x * 256;
  const int n4 = n >> 2;
  for (int i = blockIdx.x * 256 + t; i < n4; i += stride) {
    const int4 s = reinterpret_cast<const int4*>(seg)[i];
    atomicAdd(&h[s.x], 1u); atomicAdd(&h[s.y], 1u);
    atomicAdd(&h[s.z], 1u); atomicAdd(&h[s.w], 1u);
  }
  if (blockIdx.x == 0)
    for (int i = (n4 << 2) + t; i < n; i += 256) atomicAdd(&h[seg[i]], 1u);
  __syncthreads();
  if (t < NI) atomicAdd(&hist[t], h[t]);
}

// ---- K1: exclusive scan (64 entries) ----
__global__ void k_scan(const unsigned* __restrict__ hist,
                       unsigned* __restrict__ off, unsigned* __restrict__ cur) {
  if (threadIdx.x == 0) {
    unsigned acc = 0;
    for (int i = 0; i < NI; ++i) { off[i] = acc; cur[i] = acc; acc += hist[i]; }
    off[NI] = acc;
  }
}

// ---- K2: scatter point indices into instance bins ----
__global__ __launch_bounds__(256) void k_scatter(const int* __restrict__ seg,
                                                 unsigned* __restrict__ g_cur,
                                                 unsigned* __restrict__ perm, int n) {
  __shared__ int stash[8192];
  __shared__ unsigned h[NI];
  __shared__ unsigned base[NI];
  const int t = threadIdx.x;
  const int start = blockIdx.x * 8192;
  const int len = min(8192, n - start);
  if (t < NI) h[t] = 0u;
  __syncthreads();
  for (int i = t; i < len; i += 256) {
    const int s = seg[start + i];
    stash[i] = s;
    atomicAdd(&h[s], 1u);
  }
  __syncthreads();
  if (t < NI) { base[t] = atomicAdd(&g_cur[t], h[t]); h[t] = 0u; }
  __syncthreads();
  for (int i = t; i < len; i += 256) {
    const int s = stash[i];
    const unsigned r = atomicAdd(&h[s], 1u);
    perm[base[s] + r] = (unsigned)(start + i);
  }
}

// ---- K3: fused stats -> norm -> rsum -> eca -> out, per-instance flags ----
__global__ __launch_bounds__(256, 8) void k_fused(
    const float* __restrict__ f, const unsigned* __restrict__ perm,
    const unsigned* __restrict__ off, const unsigned* __restrict__ cnt,
    const float* __restrict__ ew,
    float* __restrict__ g_s, float* __restrict__ g_s2, float* __restrict__ g_rsum,
    float* __restrict__ g_inv, float* __restrict__ g_mi,
    float* __restrict__ g_A, float* __restrict__ g_B,
    unsigned* __restrict__ ctrl,   // done1[64], flag1[64], done2[64], flag2[64]
    float* __restrict__ out) {
  __shared__ float red[4][128];
  __shared__ float liv[CH], lmi[CH], lA[CH], lB[CH], lm[CH];
  __shared__ int lastf;
  unsigned* done1 = ctrl;
  unsigned* flag1 = ctrl + 64;
  unsigned* done2 = ctrl + 128;
  unsigned* flag2 = ctrl + 192;

  const int ins = blockIdx.x >> 5;
  const int k = blockIdx.x & (KB - 1);
  const unsigned lo = off[ins], len = off[ins + 1] - lo;
  const unsigned a = lo + ((len * (unsigned)k) >> 5);
  const unsigned b = lo + ((len * (unsigned)(k + 1)) >> 5);
  const int t = threadIdx.x;
  const int lane = t & 63;
  const int wv = t >> 6;           // 4 waves
  const int psub = lane >> 4;      // 4 points per wave-iter
  const int c0 = (lane & 15) << 2; // 4 channels per lane
  const float c = fmaxf((float)cnt[ins], 1.f);

  // counted-loop geometry: thread handles indices idx0, idx0+16, ... (< b)
  const unsigned idx0 = a + (unsigned)(wv * 4 + psub);
  const int rem = (int)b - (int)idx0;
  const unsigned T = (rem > 0) ? (((unsigned)rem + 15u) >> 4) : 0u;
  const unsigned T4 = T & ~3u;

#define ROW(p) reinterpret_cast<const float4*>(f + (size_t)(p) * CH + c0)

  // ---------- phase 1: stats ----------
  {
    float4 s = {0.f, 0.f, 0.f, 0.f}, s2 = {0.f, 0.f, 0.f, 0.f};
    unsigned j = 0;
    for (; j < T4; j += 4) {
      const unsigned ib = idx0 + j * 16u;
      const unsigned p0 = perm[ib];
      const unsigned p1 = perm[ib + 16u];
      const unsigned p2 = perm[ib + 32u];
      const unsigned p3 = perm[ib + 48u];
      const float4 v0 = *ROW(p0);
      const float4 v1 = *ROW(p1);
      const float4 v2 = *ROW(p2);
      const float4 v3 = *ROW(p3);
      s.x += v0.x + v1.x + v2.x + v3.x;
      s.y += v0.y + v1.y + v2.y + v3.y;
      s.z += v0.z + v1.z + v2.z + v3.z;
      s.w += v0.w + v1.w + v2.w + v3.w;
      s2.x = fmaf(v0.x, v0.x, fmaf(v1.x, v1.x, fmaf(v2.x, v2.x, fmaf(v3.x, v3.x, s2.x))));
      s2.y = fmaf(v0.y, v0.y, fmaf(v1.y, v1.y, fmaf(v2.y, v2.y, fmaf(v3.y, v3.y, s2.y))));
      s2.z = fmaf(v0.z, v0.z, fmaf(v1.z, v1.z, fmaf(v2.z, v2.z, fmaf(v3.z, v3.z, s2.z))));
      s2.w = fmaf(v0.w, v0.w, fmaf(v1.w, v1.w, fmaf(v2.w, v2.w, fmaf(v3.w, v3.w, s2.w))));
    }
    for (; j < T; ++j) {
      const unsigned p = perm[idx0 + j * 16u];
      const float4 v = *ROW(p);
      s.x += v.x; s.y += v.y; s.z += v.z; s.w += v.w;
      s2.x = fmaf(v.x, v.x, s2.x); s2.y = fmaf(v.y, v.y, s2.y);
      s2.z = fmaf(v.z, v.z, s2.z); s2.w = fmaf(v.w, v.w, s2.w);
    }
    s.x += __shfl_xor(s.x, 16); s.y += __shfl_xor(s.y, 16);
    s.z += __shfl_xor(s.z, 16); s.w += __shfl_xor(s.w, 16);
    s.x += __shfl_xor(s.x, 32); s.y += __shfl_xor(s.y, 32);
    s.z += __shfl_xor(s.z, 32); s.w += __shfl_xor(s.w, 32);
    s2.x += __shfl_xor(s2.x, 16); s2.y += __shfl_xor(s2.y, 16);
    s2.z += __shfl_xor(s2.z, 16); s2.w += __shfl_xor(s2.w, 16);
    s2.x += __shfl_xor(s2.x, 32); s2.y += __shfl_xor(s2.y, 32);
    s2.z += __shfl_xor(s2.z, 32); s2.w += __shfl_xor(s2.w, 32);
    if (psub == 0) {
      *reinterpret_cast<float4*>(&red[wv][c0]) = s;
      *reinterpret_cast<float4*>(&red[wv][64 + c0]) = s2;
    }
  }
  __syncthreads();
  if (t < 128) {
    const float v = red[0][t] + red[1][t] + red[2][t] + red[3][t];
    float* dst = (t < 64) ? (g_s + ins * CH + t) : (g_s2 + ins * CH + (t - 64));
    atomicAdd(dst, v);
  }
  __syncthreads();  // drains vmcnt before the done increment
  if (t == 0)
    lastf = (__hip_atomic_fetch_add(&done1[ins], 1u, __ATOMIC_ACQ_REL,
                                    __HIP_MEMORY_SCOPE_AGENT) == KB - 1) ? 1 : 0;
  __syncthreads();
  if (lastf) {
    if (t < CH) {
      const float st = LD_AGENT(&g_s[ins * CH + t]);
      const float s2t = LD_AGENT(&g_s2[ins * CH + t]);
      const float mu = st / c;
      const float var = fmaxf(s2t / c - mu * mu, 0.f);
      const float inv = rsqrtf(var + EPSV);
      liv[t] = inv; lmi[t] = mu * inv;
      ST_AGENT(&g_inv[ins * CH + t], inv);
      ST_AGENT(&g_mi[ins * CH + t], mu * inv);
    }
    __syncthreads();
    if (t == 0) ST_REL(&flag1[ins], 1u);
  } else {
    if (t == 0)
      while (LD_ACQ(&flag1[ins]) == 0u) __builtin_amdgcn_s_sleep(32);
    __syncthreads();
    if (t < CH) {
      liv[t] = LD_AGENT(&g_inv[ins * CH + t]);
      lmi[t] = LD_AGENT(&g_mi[ins * CH + t]);
    }
  }
  __syncthreads();

  // ---------- phase 2: rsum ----------
  {
    const float4 iv = *reinterpret_cast<const float4*>(&liv[c0]);
    const float4 mi = *reinterpret_cast<const float4*>(&lmi[c0]);
    float4 r = {0.f, 0.f, 0.f, 0.f};
    unsigned j = 0;
    for (; j < T4; j += 4) {
      const unsigned ib = idx0 + j * 16u;
      const unsigned p0 = perm[ib];
      const unsigned p1 = perm[ib + 16u];
      const unsigned p2 = perm[ib + 32u];
      const unsigned p3 = perm[ib + 48u];
      const float4 v0 = *ROW(p0);
      const float4 v1 = *ROW(p1);
      const float4 v2 = *ROW(p2);
      const float4 v3 = *ROW(p3);
      r.x += fmaxf(fmaf(v0.x, iv.x, -mi.x), 0.f) + fmaxf(fmaf(v1.x, iv.x, -mi.x), 0.f)
           + fmaxf(fmaf(v2.x, iv.x, -mi.x), 0.f) + fmaxf(fmaf(v3.x, iv.x, -mi.x), 0.f);
      r.y += fmaxf(fmaf(v0.y, iv.y, -mi.y), 0.f) + fmaxf(fmaf(v1.y, iv.y, -mi.y), 0.f)
           + fmaxf(fmaf(v2.y, iv.y, -mi.y), 0.f) + fmaxf(fmaf(v3.y, iv.y, -mi.y), 0.f);
      r.z += fmaxf(fmaf(v0.z, iv.z, -mi.z), 0.f) + fmaxf(fmaf(v1.z, iv.z, -mi.z), 0.f)
           + fmaxf(fmaf(v2.z, iv.z, -mi.z), 0.f) + fmaxf(fmaf(v3.z, iv.z, -mi.z), 0.f);
      r.w += fmaxf(fmaf(v0.w, iv.w, -mi.w), 0.f) + fmaxf(fmaf(v1.w, iv.w, -mi.w), 0.f)
           + fmaxf(fmaf(v2.w, iv.w, -mi.w), 0.f) + fmaxf(fmaf(v3.w, iv.w, -mi.w), 0.f);
    }
    for (; j < T; ++j) {
      const unsigned p = perm[idx0 + j * 16u];
      const float4 v = *ROW(p);
      r.x += fmaxf(fmaf(v.x, iv.x, -mi.x), 0.f);
      r.y += fmaxf(fmaf(v.y, iv.y, -mi.y), 0.f);
      r.z += fmaxf(fmaf(v.z, iv.z, -mi.z), 0.f);
      r.w += fmaxf(fmaf(v.w, iv.w, -mi.w), 0.f);
    }
    r.x += __shfl_xor(r.x, 16); r.y += __shfl_xor(r.y, 16);
    r.z += __shfl_xor(r.z, 16); r.w += __shfl_xor(r.w, 16);
    r.x += __shfl_xor(r.x, 32); r.y += __shfl_xor(r.y, 32);
    r.z += __shfl_xor(r.z, 32); r.w += __shfl_xor(r.w, 32);
    if (psub == 0) *reinterpret_cast<float4*>(&red[wv][c0]) = r;
  }
  __syncthreads();
  if (t < CH)
    atomicAdd(&g_rsum[ins * CH + t], red[0][t] + red[1][t] + red[2][t] + red[3][t]);
  __syncthreads();
  if (t == 0)
    lastf = (__hip_atomic_fetch_add(&done2[ins], 1u, __ATOMIC_ACQ_REL,
                                    __HIP_MEMORY_SCOPE_AGENT) == KB - 1) ? 1 : 0;
  __syncthreads();
  if (lastf) {
    if (t < CH) lm[t] = LD_AGENT(&g_rsum[ins * CH + t]) / c;
    __syncthreads();
    if (t < CH) {
      const float e0 = ew[0], e1 = ew[1], e2 = ew[2];
      const float ma = t ? lm[t - 1] : 0.f;
      const float mb = lm[t];
      const float md = (t < CH - 1) ? lm[t + 1] : 0.f;
      const float conv = e0 * ma + e1 * mb + e2 * md;
      const float w = 1.f / (1.f + expf(-conv));
      const float A = liv[t] * w, B = lmi[t] * w;
      lA[t] = A; lB[t] = B;
      ST_AGENT(&g_A[ins * CH + t], A);
      ST_AGENT(&g_B[ins * CH + t], B);
    }
    __syncthreads();
    if (t == 0) ST_REL(&flag2[ins], 1u);
  } else {
    if (t == 0)
      while (LD_ACQ(&flag2[ins]) == 0u) __builtin_amdgcn_s_sleep(32);
    __syncthreads();
    if (t < CH) {
      lA[t] = LD_AGENT(&g_A[ins * CH + t]);
      lB[t] = LD_AGENT(&g_B[ins * CH + t]);
    }
  }
  __syncthreads();

  // ---------- phase 3: out ----------
  {
    const float4 a4 = *reinterpret_cast<const float4*>(&lA[c0]);
    const float4 b4 = *reinterpret_cast<const float4*>(&lB[c0]);
    unsigned j = 0;
    for (; j < T4; j += 4) {
      const unsigned ib = idx0 + j * 16u;
      const unsigned p0 = perm[ib];
      const unsigned p1 = perm[ib + 16u];
      const unsigned p2 = perm[ib + 32u];
      const unsigned p3 = perm[ib + 48u];
      const float4 v0 = *ROW(p0);
      const float4 v1 = *ROW(p1);
      const float4 v2 = *ROW(p2);
      const float4 v3 = *ROW(p3);
      v4f o0, o1, o2, o3;
      o0.x = fmaxf(fmaf(v0.x, a4.x, -b4.x), 0.f); o0.y = fmaxf(fmaf(v0.y, a4.y, -b4.y), 0.f);
      o0.z = fmaxf(fmaf(v0.z, a4.z, -b4.z), 0.f); o0.w = fmaxf(fmaf(v0.w, a4.w, -b4.w), 0.f);
      o1.x = fmaxf(fmaf(v1.x, a4.x, -b4.x), 0.f); o1.y = fmaxf(fmaf(v1.y, a4.y, -b4.y), 0.f);
      o1.z = fmaxf(fmaf(v1.z, a4.z, -b4.z), 0.f); o1.w = fmaxf(fmaf(v1.w, a4.w, -b4.w), 0.f);
      o2.x = fmaxf(fmaf(v2.x, a4.x, -b4.x), 0.f); o2.y = fmaxf(fmaf(v2.y, a4.y, -b4.y), 0.f);
      o2.z = fmaxf(fmaf(v2.z, a4.z, -b4.z), 0.f); o2.w = fmaxf(fmaf(v2.w, a4.w, -b4.w), 0.f);
      o3.x = fmaxf(fmaf(v3.x, a4.x, -b4.x), 0.f); o3.y = fmaxf(fmaf(v3.y, a4.y, -b4.y), 0.f);
      o3.z = fmaxf(fmaf(v3.z, a4.z, -b4.z), 0.f); o3.w = fmaxf(fmaf(v3.w, a4.w, -b4.w), 0.f);
      __builtin_nontemporal_store(o0, reinterpret_cast<v4f*>(out + (size_t)p0 * CH + c0));
      __builtin_nontemporal_store(o1, reinterpret_cast<v4f*>(out + (size_t)p1 * CH + c0));
      __builtin_nontemporal_store(o2, reinterpret_cast<v4f*>(out + (size_t)p2 * CH + c0));
      __builtin_nontemporal_store(o3, reinterpret_cast<v4f*>(out + (size_t)p3 * CH + c0));
    }
    for (; j < T; ++j) {
      const unsigned p = perm[idx0 + j * 16u];
      const float4 v = *ROW(p);
      v4f o;
      o.x = fmaxf(fmaf(v.x, a4.x, -b4.x), 0.f);
      o.y = fmaxf(fmaf(v.y, a4.y, -b4.y), 0.f);
      o.z = fmaxf(fmaf(v.z, a4.z, -b4.z), 0.f);
      o.w = fmaxf(fmaf(v.w, a4.w, -b4.w), 0.f);
      __builtin_nontemporal_store(o, reinterpret_cast<v4f*>(out + (size_t)p * CH + c0));
    }
  }
#undef ROW
}

// ================= fallback path (ws too small for perm) =================
__global__ __launch_bounds__(256) void k_musig(const float* __restrict__ g_s,
                                               const float* __restrict__ g_s2,
                                               const unsigned* __restrict__ cnt,
                                               float* __restrict__ g_inv,
                                               float* __restrict__ g_mi) {
  const int i = blockIdx.x * 256 + threadIdx.x;
  const float c = fmaxf((float)cnt[i >> 6], 1.f);
  const float mu = g_s[i] / c;
  const float var = fmaxf(g_s2[i] / c - mu * mu, 0.f);
  const float inv = rsqrtf(var + EPSV);
  g_inv[i] = inv;
  g_mi[i] = mu * inv;
}

__global__ __launch_bounds__(256) void k_eca(const float* __restrict__ g_rsum,
                                             const unsigned* __restrict__ cnt,
                                             const float* __restrict__ ew,
                                             const float* __restrict__ g_inv,
                                             const float* __restrict__ g_mi,
                                             float* __restrict__ g_A,
                                             float* __restrict__ g_B) {
  __shared__ float m[NI * CH];
  const int t = threadIdx.x;
  for (int i = t; i < NI * CH; i += 256)
    m[i] = g_rsum[i] / fmaxf((float)cnt[i >> 6], 1.f);
  __syncthreads();
  const float e0 = ew[0], e1 = ew[1], e2 = ew[2];
  for (int i = t; i < NI * CH; i += 256) {
    const int cch = i & 63;
    const float a = cch ? m[i - 1] : 0.f;
    const float b = m[i];
    const float d = (cch < 63) ? m[i + 1] : 0.f;
    const float conv = e0 * a + e1 * b + e2 * d;
    const float w = 1.f / (1.f + expf(-conv));
    g_A[i] = g_inv[i] * w;
    g_B[i] = g_mi[i] * w;
  }
}

__global__ __launch_bounds__(256) void k_out(const float* __restrict__ f,
                                             const int* __restrict__ seg,
                                             const float* __restrict__ g_A,
                                             const float* __restrict__ g_B,
                                             float* __restrict__ out, int n) {
  __shared__ float tA[NI * PADT];
  __shared__ float tB[NI * PADT];
  const int t = threadIdx.x;
  for (int i = t; i < NI * CH; i += 256) {
    const int a = (i >> 6) * PADT + (i & 63);
    tA[a] = g_A[i];
    tB[a] = g_B[i];
  }
  __syncthreads();
  const int sub = t & 15, c0 = sub << 2, pib = t >> 4;
  const int pstride = gridDim.x << 4;
  for (int p = (blockIdx.x << 4) + pib; p < n; p += pstride) {
    const float4 v = *reinterpret_cast<const float4*>(f + (size_t)p * CH + c0);
    const int tb = seg[p] * PADT + c0;
    const float4 a = *reinterpret_cast<const float4*>(tA + tb);
    const float4 b = *reinterpret_cast<const float4*>(tB + tb);
    float4 o;
    o.x = fmaxf(fmaf(v.x, a.x, -b.x), 0.f);
    o.y = fmaxf(fmaf(v.y, a.y, -b.y), 0.f);
    o.z = fmaxf(fmaf(v.z, a.z, -b.z), 0.f);
    o.w = fmaxf(fmaf(v.w, a.w, -b.w), 0.f);
    *reinterpret_cast<float4*>(out + (size_t)p * CH + c0) = o;
  }
}

__global__ __launch_bounds__(1024) void k_stats_f(const float* __restrict__ f,
                                                  const int* __restrict__ seg,
                                                  float* __restrict__ g_s,
                                                  float* __restrict__ g_s2,
                                                  unsigned* __restrict__ g_cnt, int n) {
  __shared__ float ls[NI * PADW];
  __shared__ float ls2[NI * PADW];
  __shared__ unsigned lcnt[NI];
  const int t = threadIdx.x;
  for (int i = t; i < NI * PADW; i += 1024) { ls[i] = 0.f; ls2[i] = 0.f; }
  if (t < NI) lcnt[t] = 0u;
  __syncthreads();
  const int sub = t & 15, c0 = sub << 2, pib = t >> 4;
  const int pstride = gridDim.x << 6;
  for (int p = (blockIdx.x << 6) + pib; p < n; p += pstride) {
    const float4 v = *reinterpret_cast<const float4*>(f + (size_t)p * CH + c0);
    const int b = seg[p] * PADW + c0;
    atomicAdd(&ls[b + 0], v.x); atomicAdd(&ls[b + 1], v.y);
    atomicAdd(&ls[b + 2], v.z); atomicAdd(&ls[b + 3], v.w);
    atomicAdd(&ls2[b + 0], v.x * v.x); atomicAdd(&ls2[b + 1], v.y * v.y);
    atomicAdd(&ls2[b + 2], v.z * v.z); atomicAdd(&ls2[b + 3], v.w * v.w);
    if (sub == 0) atomicAdd(&lcnt[seg[p]], 1u);
  }
  __syncthreads();
  for (int i = t; i < NI * CH; i += 1024) {
    const int a = (i >> 6) * PADW + (i & 63);
    atomicAdd(&g_s[i], ls[a]);
    atomicAdd(&g_s2[i], ls2[a]);
  }
  if (t < NI) atomicAdd(&g_cnt[t], lcnt[t]);
}

__global__ __launch_bounds__(1024) void k_rsum_f(const float* __restrict__ f,
                                                 const int* __restrict__ seg,
                                                 const float* __restrict__ g_inv,
                                                 const float* __restrict__ g_mi,
                                                 float* __restrict__ g_rsum, int n) {
  __shared__ float tinv[NI * CH];
  __shared__ float tmi[NI * CH];
  __shared__ float lr[NI * PADW];
  const int t = threadIdx.x;
  for (int i = t; i < NI * CH; i += 1024) { tinv[i] = g_inv[i]; tmi[i] = g_mi[i]; }
  for (int i = t; i < NI * PADW; i += 1024) lr[i] = 0.f;
  __syncthreads();
  const int sub = t & 15, c0 = sub << 2, pib = t >> 4;
  const int pstride = gridDim.x << 6;
  for (int p = (blockIdx.x << 6) + pib; p < n; p += pstride) {
    const float4 v = *reinterpret_cast<const float4*>(f + (size_t)p * CH + c0);
    const int ins = seg[p];
    const int tb = (ins << 6) + c0;
    const float4 iv = *reinterpret_cast<const float4*>(tinv + tb);
    const float4 mi = *reinterpret_cast<const float4*>(tmi + tb);
    const int b = ins * PADW + c0;
    atomicAdd(&lr[b + 0], fmaxf(fmaf(v.x, iv.x, -mi.x), 0.f));
    atomicAdd(&lr[b + 1], fmaxf(fmaf(v.y, iv.y, -mi.y), 0.f));
    atomicAdd(&lr[b + 2], fmaxf(fmaf(v.z, iv.z, -mi.z), 0.f));
    atomicAdd(&lr[b + 3], fmaxf(fmaf(v.w, iv.w, -mi.w), 0.f));
  }
  __syncthreads();
  for (int i = t; i < NI * CH; i += 1024)
    atomicAdd(&g_rsum[i], lr[(i >> 6) * PADW + (i & 63)]);
}

// ================= launch =================
extern "C" void kernel_launch(void* const* d_in, const int* in_sizes, int n_in,
                              void* d_out, int out_size, void* d_ws, size_t ws_size,
                              hipStream_t stream) {
  const float* f   = (const float*)d_in[0];
  const int*   seg = (const int*)d_in[1];
  const float* ew  = (const float*)d_in[2];
  float* out = (float*)d_out;
  const int n = in_sizes[1];

  // ws layout (float offsets)
  float* ws      = (float*)d_ws;
  float* g_s     = ws;                       // 4096
  float* g_s2    = ws + 4096;                // 4096
  float* g_rsum  = ws + 8192;                // 4096
  unsigned* hist = (unsigned*)(ws + 12288);  // 64 (= counts)
  unsigned* off  = hist + 64;                // 65
  unsigned* cur  = off + 65;                 // 64
  unsigned* ctrl = (unsigned*)(ws + 12544);  // 256: done1,flag1,done2,flag2
  float* g_inv   = ws + 12800;               // 4096
  float* g_mi    = ws + 16896;               // 4096
  float* g_A     = ws + 20992;               // 4096
  float* g_B     = ws + 25088;               // 4096
  unsigned* perm = (unsigned*)(ws + 29184);  // n
  const size_t need = (size_t)(29184 + n) * 4;

  // zero accumulators + hist/off/cur + control flags (12800 floats)
  (void)hipMemsetAsync(d_ws, 0, 12800 * sizeof(float), stream);

  if (ws_size >= need) {
    k_hist<<<256, 256, 0, stream>>>(seg, hist, n);
    k_scan<<<1, 64, 0, stream>>>(hist, off, cur);
    k_scatter<<<(n + 8191) / 8192, 256, 0, stream>>>(seg, cur, perm, n);
    k_fused<<<NI * KB, 256, 0, stream>>>(f, perm, off, hist, ew,
                                         g_s, g_s2, g_rsum, g_inv, g_mi,
                                         g_A, g_B, ctrl, out);
  } else {
    k_stats_f<<<512, 1024, 0, stream>>>(f, seg, g_s, g_s2, hist, n);
    k_musig<<<16, 256, 0, stream>>>(g_s, g_s2, hist, g_inv, g_mi);
    k_rsum_f<<<512, 1024, 0, stream>>>(f, seg, g_inv, g_mi, g_rsum, n);
    k_eca<<<1, 256, 0, stream>>>(g_rsum, hist, ew, g_inv, g_mi, g_A, g_B);
    k_out<<<2048, 256, 0, stream>>>(f, seg, g_A, g_B, out, n);
  }
}

// Round 6
// 461.224 us; speedup vs baseline: 1.5831x; 1.5831x over previous
//
#include <hip/hip_runtime.h>

#define NI 64      // instances
#define CH 64      // channels
#define EPSV 1e-5f
#define KB 32      // blocks per instance in fused kernel
#define PADT 66    // padded LDS table row for k_out (fallback)
#define PADW 65    // fallback-path padding

// ---- K0: per-instance counts ----
__global__ __launch_bounds__(256) void k_hist(const int* __restrict__ seg,
                                              unsigned* __restrict__ hist, int n) {
  __shared__ unsigned h[NI];
  const int t = threadIdx.x;
  if (t < NI) h[t] = 0u;
  __syncthreads();
  const int stride = gridDim.x * 256;
  const int n4 = n >> 2;
  for (int i = blockIdx.x * 256 + t; i < n4; i += stride) {
    const int4 s = reinterpret_cast<const int4*>(seg)[i];
    atomicAdd(&h[s.x], 1u); atomicAdd(&h[s.y], 1u);
    atomicAdd(&h[s.z], 1u); atomicAdd(&h[s.w], 1u);
  }
  if (blockIdx.x == 0)
    for (int i = (n4 << 2) + t; i < n; i += 256) atomicAdd(&h[seg[i]], 1u);
  __syncthreads();
  if (t < NI) atomicAdd(&hist[t], h[t]);
}

// ---- K1: exclusive scan (64 entries) ----
__global__ void k_scan(const unsigned* __restrict__ hist,
                       unsigned* __restrict__ off, unsigned* __restrict__ cur) {
  if (threadIdx.x == 0) {
    unsigned acc = 0;
    for (int i = 0; i < NI; ++i) { off[i] = acc; cur[i] = acc; acc += hist[i]; }
    off[NI] = acc;
  }
}

// ---- K2: scatter point indices into instance bins ----
__global__ __launch_bounds__(256) void k_scatter(const int* __restrict__ seg,
                                                 unsigned* __restrict__ g_cur,
                                                 unsigned* __restrict__ perm, int n) {
  __shared__ int stash[8192];
  __shared__ unsigned h[NI];
  __shared__ unsigned base[NI];
  const int t = threadIdx.x;
  const int start = blockIdx.x * 8192;
  const int len = min(8192, n - start);
  if (t < NI) h[t] = 0u;
  __syncthreads();
  for (int i = t; i < len; i += 256) {
    const int s = seg[start + i];
    stash[i] = s;
    atomicAdd(&h[s], 1u);
  }
  __syncthreads();
  if (t < NI) { base[t] = atomicAdd(&g_cur[t], h[t]); h[t] = 0u; }
  __syncthreads();
  for (int i = t; i < len; i += 256) {
    const int s = stash[i];
    const unsigned r = atomicAdd(&h[s], 1u);
    perm[base[s] + r] = (unsigned)(start + i);
  }
}

// ---- K3: fused stats -> norm -> rsum -> eca -> out, per-instance flags ----
// Identical to round-3 kernel EXCEPT phase 1 uses a counted x2-unrolled gather.
__global__ __launch_bounds__(256, 8) void k_fused(
    const float* __restrict__ f, const unsigned* __restrict__ perm,
    const unsigned* __restrict__ off, const unsigned* __restrict__ cnt,
    const float* __restrict__ ew,
    float* __restrict__ g_s, float* __restrict__ g_s2, float* __restrict__ g_rsum,
    float* __restrict__ g_inv, float* __restrict__ g_mi,
    float* __restrict__ g_A, float* __restrict__ g_B,
    unsigned* __restrict__ ctrl,   // done1[64], flag1[64], done2[64], flag2[64]
    float* __restrict__ out) {
  __shared__ float red[4][128];
  __shared__ float liv[CH], lmi[CH], lA[CH], lB[CH], lm[CH];
  __shared__ int lastf;
  unsigned* done1 = ctrl;
  unsigned* flag1 = ctrl + 64;
  unsigned* done2 = ctrl + 128;
  unsigned* flag2 = ctrl + 192;

  const int ins = blockIdx.x >> 5;
  const int k = blockIdx.x & (KB - 1);
  const unsigned lo = off[ins], len = off[ins + 1] - lo;
  const unsigned a = lo + ((len * (unsigned)k) >> 5);
  const unsigned b = lo + ((len * (unsigned)(k + 1)) >> 5);
  const int t = threadIdx.x;
  const int lane = t & 63;
  const int wv = t >> 6;           // 4 waves
  const int psub = lane >> 4;      // 4 points per wave-iter
  const int c0 = (lane & 15) << 2; // 4 channels per lane
  const float c = fmaxf((float)cnt[ins], 1.f);

  const unsigned idx0 = a + (unsigned)(wv * 4 + psub);
  const int rem = (int)b - (int)idx0;
  const unsigned T = (rem > 0) ? (((unsigned)rem + 15u) >> 4) : 0u;
  const unsigned T2 = T & ~1u;

#define ROW(p) reinterpret_cast<const float4*>(f + (size_t)(p) * CH + c0)

  // ---------- phase 1: stats (x2-unrolled gather) ----------
  {
    float4 s = {0.f, 0.f, 0.f, 0.f}, s2 = {0.f, 0.f, 0.f, 0.f};
    unsigned j = 0;
    for (; j < T2; j += 2) {
      const unsigned ib = idx0 + j * 16u;
      const unsigned p0 = perm[ib];
      const unsigned p1 = perm[ib + 16u];
      const float4 v0 = *ROW(p0);
      const float4 v1 = *ROW(p1);
      s.x += v0.x + v1.x;
      s.y += v0.y + v1.y;
      s.z += v0.z + v1.z;
      s.w += v0.w + v1.w;
      s2.x = fmaf(v0.x, v0.x, fmaf(v1.x, v1.x, s2.x));
      s2.y = fmaf(v0.y, v0.y, fmaf(v1.y, v1.y, s2.y));
      s2.z = fmaf(v0.z, v0.z, fmaf(v1.z, v1.z, s2.z));
      s2.w = fmaf(v0.w, v0.w, fmaf(v1.w, v1.w, s2.w));
    }
    for (; j < T; ++j) {
      const unsigned p = perm[idx0 + j * 16u];
      const float4 v = *ROW(p);
      s.x += v.x; s.y += v.y; s.z += v.z; s.w += v.w;
      s2.x = fmaf(v.x, v.x, s2.x); s2.y = fmaf(v.y, v.y, s2.y);
      s2.z = fmaf(v.z, v.z, s2.z); s2.w = fmaf(v.w, v.w, s2.w);
    }
    s.x += __shfl_xor(s.x, 16); s.y += __shfl_xor(s.y, 16);
    s.z += __shfl_xor(s.z, 16); s.w += __shfl_xor(s.w, 16);
    s.x += __shfl_xor(s.x, 32); s.y += __shfl_xor(s.y, 32);
    s.z += __shfl_xor(s.z, 32); s.w += __shfl_xor(s.w, 32);
    s2.x += __shfl_xor(s2.x, 16); s2.y += __shfl_xor(s2.y, 16);
    s2.z += __shfl_xor(s2.z, 16); s2.w += __shfl_xor(s2.w, 16);
    s2.x += __shfl_xor(s2.x, 32); s2.y += __shfl_xor(s2.y, 32);
    s2.z += __shfl_xor(s2.z, 32); s2.w += __shfl_xor(s2.w, 32);
    if (psub == 0) {
      *reinterpret_cast<float4*>(&red[wv][c0]) = s;
      *reinterpret_cast<float4*>(&red[wv][64 + c0]) = s2;
    }
  }
  __syncthreads();
  if (t < 128) {
    const float v = red[0][t] + red[1][t] + red[2][t] + red[3][t];
    float* dst = (t < 64) ? (g_s + ins * CH + t) : (g_s2 + ins * CH + (t - 64));
    atomicAdd(dst, v);
  }
  __syncthreads();  // drains vmcnt before the done increment
  if (t == 0) lastf = (atomicAdd(&done1[ins], 1u) == KB - 1) ? 1 : 0;
  __syncthreads();
  if (lastf) {
    if (t < CH) {
      const float st = atomicAdd(&g_s[ins * CH + t], 0.f);
      const float s2t = atomicAdd(&g_s2[ins * CH + t], 0.f);
      const float mu = st / c;
      const float var = fmaxf(s2t / c - mu * mu, 0.f);
      const float inv = rsqrtf(var + EPSV);
      liv[t] = inv; lmi[t] = mu * inv;
      atomicExch(&g_inv[ins * CH + t], inv);
      atomicExch(&g_mi[ins * CH + t], mu * inv);
    }
    __syncthreads();
    if (t == 0) atomicExch(&flag1[ins], 1u);
  } else {
    if (t == 0)
      while (atomicAdd(&flag1[ins], 0u) == 0u) __builtin_amdgcn_s_sleep(8);
    __syncthreads();
    if (t < CH) {
      liv[t] = atomicAdd(&g_inv[ins * CH + t], 0.f);
      lmi[t] = atomicAdd(&g_mi[ins * CH + t], 0.f);
    }
  }
  __syncthreads();

  // ---------- phase 2: rsum (round-3 form) ----------
  {
    const float4 iv = *reinterpret_cast<const float4*>(&liv[c0]);
    const float4 mi = *reinterpret_cast<const float4*>(&lmi[c0]);
    float4 r = {0.f, 0.f, 0.f, 0.f};
    for (unsigned i = idx0; i < b; i += 16) {
      const unsigned p = perm[i];
      const float4 v = *ROW(p);
      r.x += fmaxf(fmaf(v.x, iv.x, -mi.x), 0.f);
      r.y += fmaxf(fmaf(v.y, iv.y, -mi.y), 0.f);
      r.z += fmaxf(fmaf(v.z, iv.z, -mi.z), 0.f);
      r.w += fmaxf(fmaf(v.w, iv.w, -mi.w), 0.f);
    }
    r.x += __shfl_xor(r.x, 16); r.y += __shfl_xor(r.y, 16);
    r.z += __shfl_xor(r.z, 16); r.w += __shfl_xor(r.w, 16);
    r.x += __shfl_xor(r.x, 32); r.y += __shfl_xor(r.y, 32);
    r.z += __shfl_xor(r.z, 32); r.w += __shfl_xor(r.w, 32);
    if (psub == 0) *reinterpret_cast<float4*>(&red[wv][c0]) = r;
  }
  __syncthreads();
  if (t < CH)
    atomicAdd(&g_rsum[ins * CH + t], red[0][t] + red[1][t] + red[2][t] + red[3][t]);
  __syncthreads();
  if (t == 0) lastf = (atomicAdd(&done2[ins], 1u) == KB - 1) ? 1 : 0;
  __syncthreads();
  if (lastf) {
    if (t < CH) lm[t] = atomicAdd(&g_rsum[ins * CH + t], 0.f) / c;
    __syncthreads();
    if (t < CH) {
      const float e0 = ew[0], e1 = ew[1], e2 = ew[2];
      const float ma = t ? lm[t - 1] : 0.f;
      const float mb = lm[t];
      const float md = (t < CH - 1) ? lm[t + 1] : 0.f;
      const float conv = e0 * ma + e1 * mb + e2 * md;
      const float w = 1.f / (1.f + expf(-conv));
      const float A = liv[t] * w, B = lmi[t] * w;
      lA[t] = A; lB[t] = B;
      atomicExch(&g_A[ins * CH + t], A);
      atomicExch(&g_B[ins * CH + t], B);
    }
    __syncthreads();
    if (t == 0) atomicExch(&flag2[ins], 1u);
  } else {
    if (t == 0)
      while (atomicAdd(&flag2[ins], 0u) == 0u) __builtin_amdgcn_s_sleep(8);
    __syncthreads();
    if (t < CH) {
      lA[t] = atomicAdd(&g_A[ins * CH + t], 0.f);
      lB[t] = atomicAdd(&g_B[ins * CH + t], 0.f);
    }
  }
  __syncthreads();

  // ---------- phase 3: out (round-3 form, plain stores) ----------
  {
    const float4 a4 = *reinterpret_cast<const float4*>(&lA[c0]);
    const float4 b4 = *reinterpret_cast<const float4*>(&lB[c0]);
    for (unsigned i = idx0; i < b; i += 16) {
      const unsigned p = perm[i];
      const float4 v = *ROW(p);
      float4 o;
      o.x = fmaxf(fmaf(v.x, a4.x, -b4.x), 0.f);
      o.y = fmaxf(fmaf(v.y, a4.y, -b4.y), 0.f);
      o.z = fmaxf(fmaf(v.z, a4.z, -b4.z), 0.f);
      o.w = fmaxf(fmaf(v.w, a4.w, -b4.w), 0.f);
      *reinterpret_cast<float4*>(out + (size_t)p * CH + c0) = o;
    }
  }
#undef ROW
}

// ================= fallback path (ws too small for perm) =================
__global__ __launch_bounds__(256) void k_musig(const float* __restrict__ g_s,
                                               const float* __restrict__ g_s2,
                                               const unsigned* __restrict__ cnt,
                                               float* __restrict__ g_inv,
                                               float* __restrict__ g_mi) {
  const int i = blockIdx.x * 256 + threadIdx.x;
  const float c = fmaxf((float)cnt[i >> 6], 1.f);
  const float mu = g_s[i] / c;
  const float var = fmaxf(g_s2[i] / c - mu * mu, 0.f);
  const float inv = rsqrtf(var + EPSV);
  g_inv[i] = inv;
  g_mi[i] = mu * inv;
}

__global__ __launch_bounds__(256) void k_eca(const float* __restrict__ g_rsum,
                                             const unsigned* __restrict__ cnt,
                                             const float* __restrict__ ew,
                                             const float* __restrict__ g_inv,
                                             const float* __restrict__ g_mi,
                                             float* __restrict__ g_A,
                                             float* __restrict__ g_B) {
  __shared__ float m[NI * CH];
  const int t = threadIdx.x;
  for (int i = t; i < NI * CH; i += 256)
    m[i] = g_rsum[i] / fmaxf((float)cnt[i >> 6], 1.f);
  __syncthreads();
  const float e0 = ew[0], e1 = ew[1], e2 = ew[2];
  for (int i = t; i < NI * CH; i += 256) {
    const int cch = i & 63;
    const float a = cch ? m[i - 1] : 0.f;
    const float b = m[i];
    const float d = (cch < 63) ? m[i + 1] : 0.f;
    const float conv = e0 * a + e1 * b + e2 * d;
    const float w = 1.f / (1.f + expf(-conv));
    g_A[i] = g_inv[i] * w;
    g_B[i] = g_mi[i] * w;
  }
}

__global__ __launch_bounds__(256) void k_out(const float* __restrict__ f,
                                             const int* __restrict__ seg,
                                             const float* __restrict__ g_A,
                                             const float* __restrict__ g_B,
                                             float* __restrict__ out, int n) {
  __shared__ float tA[NI * PADT];
  __shared__ float tB[NI * PADT];
  const int t = threadIdx.x;
  for (int i = t; i < NI * CH; i += 256) {
    const int a = (i >> 6) * PADT + (i & 63);
    tA[a] = g_A[i];
    tB[a] = g_B[i];
  }
  __syncthreads();
  const int sub = t & 15, c0 = sub << 2, pib = t >> 4;
  const int pstride = gridDim.x << 4;
  for (int p = (blockIdx.x << 4) + pib; p < n; p += pstride) {
    const float4 v = *reinterpret_cast<const float4*>(f + (size_t)p * CH + c0);
    const int tb = seg[p] * PADT + c0;
    const float4 a = *reinterpret_cast<const float4*>(tA + tb);
    const float4 b = *reinterpret_cast<const float4*>(tB + tb);
    float4 o;
    o.x = fmaxf(fmaf(v.x, a.x, -b.x), 0.f);
    o.y = fmaxf(fmaf(v.y, a.y, -b.y), 0.f);
    o.z = fmaxf(fmaf(v.z, a.z, -b.z), 0.f);
    o.w = fmaxf(fmaf(v.w, a.w, -b.w), 0.f);
    *reinterpret_cast<float4*>(out + (size_t)p * CH + c0) = o;
  }
}

__global__ __launch_bounds__(1024) void k_stats_f(const float* __restrict__ f,
                                                  const int* __restrict__ seg,
                                                  float* __restrict__ g_s,
                                                  float* __restrict__ g_s2,
                                                  unsigned* __restrict__ g_cnt, int n) {
  __shared__ float ls[NI * PADW];
  __shared__ float ls2[NI * PADW];
  __shared__ unsigned lcnt[NI];
  const int t = threadIdx.x;
  for (int i = t; i < NI * PADW; i += 1024) { ls[i] = 0.f; ls2[i] = 0.f; }
  if (t < NI) lcnt[t] = 0u;
  __syncthreads();
  const int sub = t & 15, c0 = sub << 2, pib = t >> 4;
  const int pstride = gridDim.x << 6;
  for (int p = (blockIdx.x << 6) + pib; p < n; p += pstride) {
    const float4 v = *reinterpret_cast<const float4*>(f + (size_t)p * CH + c0);
    const int b = seg[p] * PADW + c0;
    atomicAdd(&ls[b + 0], v.x); atomicAdd(&ls[b + 1], v.y);
    atomicAdd(&ls[b + 2], v.z); atomicAdd(&ls[b + 3], v.w);
    atomicAdd(&ls2[b + 0], v.x * v.x); atomicAdd(&ls2[b + 1], v.y * v.y);
    atomicAdd(&ls2[b + 2], v.z * v.z); atomicAdd(&ls2[b + 3], v.w * v.w);
    if (sub == 0) atomicAdd(&lcnt[seg[p]], 1u);
  }
  __syncthreads();
  for (int i = t; i < NI * CH; i += 1024) {
    const int a = (i >> 6) * PADW + (i & 63);
    atomicAdd(&g_s[i], ls[a]);
    atomicAdd(&g_s2[i], ls2[a]);
  }
  if (t < NI) atomicAdd(&g_cnt[t], lcnt[t]);
}

__global__ __launch_bounds__(1024) void k_rsum_f(const float* __restrict__ f,
                                                 const int* __restrict__ seg,
                                                 const float* __restrict__ g_inv,
                                                 const float* __restrict__ g_mi,
                                                 float* __restrict__ g_rsum, int n) {
  __shared__ float tinv[NI * CH];
  __shared__ float tmi[NI * CH];
  __shared__ float lr[NI * PADW];
  const int t = threadIdx.x;
  for (int i = t; i < NI * CH; i += 1024) { tinv[i] = g_inv[i]; tmi[i] = g_mi[i]; }
  for (int i = t; i < NI * PADW; i += 1024) lr[i] = 0.f;
  __syncthreads();
  const int sub = t & 15, c0 = sub << 2, pib = t >> 4;
  const int pstride = gridDim.x << 6;
  for (int p = (blockIdx.x << 6) + pib; p < n; p += pstride) {
    const float4 v = *reinterpret_cast<const float4*>(f + (size_t)p * CH + c0);
    const int ins = seg[p];
    const int tb = (ins << 6) + c0;
    const float4 iv = *reinterpret_cast<const float4*>(tinv + tb);
    const float4 mi = *reinterpret_cast<const float4*>(tmi + tb);
    const int b = ins * PADW + c0;
    atomicAdd(&lr[b + 0], fmaxf(fmaf(v.x, iv.x, -mi.x), 0.f));
    atomicAdd(&lr[b + 1], fmaxf(fmaf(v.y, iv.y, -mi.y), 0.f));
    atomicAdd(&lr[b + 2], fmaxf(fmaf(v.z, iv.z, -mi.z), 0.f));
    atomicAdd(&lr[b + 3], fmaxf(fmaf(v.w, iv.w, -mi.w), 0.f));
  }
  __syncthreads();
  for (int i = t; i < NI * CH; i += 1024)
    atomicAdd(&g_rsum[i], lr[(i >> 6) * PADW + (i & 63)]);
}

// ================= launch =================
extern "C" void kernel_launch(void* const* d_in, const int* in_sizes, int n_in,
                              void* d_out, int out_size, void* d_ws, size_t ws_size,
                              hipStream_t stream) {
  const float* f   = (const float*)d_in[0];
  const int*   seg = (const int*)d_in[1];
  const float* ew  = (const float*)d_in[2];
  float* out = (float*)d_out;
  const int n = in_sizes[1];

  // ws layout (float offsets)
  float* ws      = (float*)d_ws;
  float* g_s     = ws;                       // 4096
  float* g_s2    = ws + 4096;                // 4096
  float* g_rsum  = ws + 8192;                // 4096
  unsigned* hist = (unsigned*)(ws + 12288);  // 64 (= counts)
  unsigned* off  = hist + 64;                // 65
  unsigned* cur  = off + 65;                 // 64
  unsigned* ctrl = (unsigned*)(ws + 12544);  // 256: done1,flag1,done2,flag2
  float* g_inv   = ws + 12800;               // 4096
  float* g_mi    = ws + 16896;               // 4096
  float* g_A     = ws + 20992;               // 4096
  float* g_B     = ws + 25088;               // 4096
  unsigned* perm = (unsigned*)(ws + 29184);  // n
  const size_t need = (size_t)(29184 + n) * 4;

  // zero accumulators + hist/off/cur + control flags (12800 floats)
  (void)hipMemsetAsync(d_ws, 0, 12800 * sizeof(float), stream);

  if (ws_size >= need) {
    k_hist<<<256, 256, 0, stream>>>(seg, hist, n);
    k_scan<<<1, 64, 0, stream>>>(hist, off, cur);
    k_scatter<<<(n + 8191) / 8192, 256, 0, stream>>>(seg, cur, perm, n);
    k_fused<<<NI * KB, 256, 0, stream>>>(f, perm, off, hist, ew,
                                         g_s, g_s2, g_rsum, g_inv, g_mi,
                                         g_A, g_B, ctrl, out);
  } else {
    k_stats_f<<<512, 1024, 0, stream>>>(f, seg, g_s, g_s2, hist, n);
    k_musig<<<16, 256, 0, stream>>>(g_s, g_s2, hist, g_inv, g_mi);
    k_rsum_f<<<512, 1024, 0, stream>>>(f, seg, g_inv, g_mi, g_rsum, n);
    k_eca<<<1, 256, 0, stream>>>(g_rsum, hist, ew, g_inv, g_mi, g_A, g_B);
    k_out<<<2048, 256, 0, stream>>>(f, seg, g_A, g_B, out, n);
  }
}